// Round 1
// baseline (783.522 us; speedup 1.0000x reference)
//
#include <hip/hip_runtime.h>

#define DT 0.1f
#define NSTEPS 10

__device__ __forceinline__ float fast_tanh(float x) {
    // tanh(x) = 1 - 2/(exp(2x)+1); exp via hw exp2, div via hw rcp.
    float e = __expf(2.0f * x);
    return 1.0f - 2.0f * __builtin_amdgcn_rcpf(e + 1.0f);
}

__device__ __forceinline__ void policy_eval(
    const float* __restrict__ w1, const float* __restrict__ b1,
    const float* __restrict__ w2, const float* __restrict__ b2,
    const float* __restrict__ w3, const float* __restrict__ b3,
    float c0, float c1, float c2, float c3,
    float& o0, float& o1)
{
    float h[8];
#pragma unroll
    for (int j = 0; j < 8; ++j) {
        float a = b1[j];
        a = fmaf(w1[j * 4 + 0], c0, a);
        a = fmaf(w1[j * 4 + 1], c1, a);
        a = fmaf(w1[j * 4 + 2], c2, a);
        a = fmaf(w1[j * 4 + 3], c3, a);
        h[j] = fast_tanh(a);
    }
    float g[8];
#pragma unroll
    for (int j = 0; j < 8; ++j) {
        float a = b2[j];
#pragma unroll
        for (int k = 0; k < 8; ++k) a = fmaf(w2[j * 8 + k], h[k], a);
        g[j] = fast_tanh(a);
    }
    float t0 = b3[0], t1 = b3[1];
#pragma unroll
    for (int k = 0; k < 8; ++k) {
        t0 = fmaf(w3[k], g[k], t0);
        t1 = fmaf(w3[8 + k], g[k], t1);
    }
    o0 = t0;
    o1 = t1;
}

__global__ void __launch_bounds__(256) rollout_kernel(
    const float* __restrict__ s_star, const float* __restrict__ s0,
    const float* __restrict__ fc1_w, const float* __restrict__ fc1_b,
    const float* __restrict__ fc2_w, const float* __restrict__ fc2_b,
    const float* __restrict__ rc1_w, const float* __restrict__ rc1_b,
    const float* __restrict__ rc2_w, const float* __restrict__ rc2_b,
    const float* __restrict__ rc3_w, const float* __restrict__ rc3_b,
    const float* __restrict__ rr1_w, const float* __restrict__ rr1_b,
    const float* __restrict__ rr2_w, const float* __restrict__ rr2_b,
    const float* __restrict__ rr3_w, const float* __restrict__ rr3_b,
    float* __restrict__ out, int B)
{
    int i = blockIdx.x * blockDim.x + threadIdx.x;
    if (i >= B) return;

    float2 ss = reinterpret_cast<const float2*>(s_star)[i];
    float2 s  = reinterpret_cast<const float2*>(s0)[i];

    // Fuse the linear predictor: ah = fc2(fc1(x)) = A @ [s, s_star] + cb
    // A[r][c] = sum_j fc2_w[r][j] * fc1_w[j][c]; cb[r] = fc2_w[r]·fc1_b + fc2_b[r]
    float A00, A01, A10, A11, d0, d1;
    {
        float A[2][4];
        float cb[2];
#pragma unroll
        for (int r = 0; r < 2; ++r) {
#pragma unroll
            for (int c = 0; c < 4; ++c) {
                float a = 0.0f;
#pragma unroll
                for (int j = 0; j < 4; ++j)
                    a = fmaf(fc2_w[r * 4 + j], fc1_w[j * 4 + c], a);
                A[r][c] = a;
            }
            float b = fc2_b[r];
#pragma unroll
            for (int j = 0; j < 4; ++j) b = fmaf(fc2_w[r * 4 + j], fc1_b[j], b);
            cb[r] = b;
        }
        A00 = A[0][0]; A01 = A[0][1]; A10 = A[1][0]; A11 = A[1][1];
        // s_star part is constant over steps: fold into d
        d0 = fmaf(A[0][2], ss.x, fmaf(A[0][3], ss.y, cb[0]));
        d1 = fmaf(A[1][2], ss.x, fmaf(A[1][3], ss.y, cb[1]));
    }

    // ideal human action: (-1,0) if s_star.x > 0.5 else (1,0)
    float ahs0 = (ss.x > 0.5f) ? -1.0f : 1.0f;

    float sx = s.x, sy = s.y;
    float err = 0.0f;

#pragma unroll 1
    for (int t = 0; t < NSTEPS; ++t) {
        float ah0 = fmaf(A00, sx, fmaf(A01, sy, d0));
        float ah1 = fmaf(A10, sx, fmaf(A11, sy, d1));

        float arr0, arr1, ar0, ar1;
        // robot (detached) policy
        policy_eval(rr1_w, rr1_b, rr2_w, rr2_b, rr3_w, rr3_b,
                    sx, sy, ah0, ah1, arr0, arr1);
        // conditioned policy (drives the state)
        policy_eval(rc1_w, rc1_b, rc2_w, rc2_b, rc3_w, rc3_b,
                    sx, sy, ah0, ah1, ar0, ar1);

        sx = fmaf(DT, ar0, sx);
        sy = fmaf(DT, ar1, sy);

        float dx = ss.x - sx, dy = ss.y - sy;
        float e1 = __builtin_amdgcn_sqrtf(fmaf(dx, dx, dy * dy));
        float ux = arr0 - ar0, uy = arr1 - ar1;
        float e2 = __builtin_amdgcn_sqrtf(fmaf(ux, ux, uy * uy));
        float vx = ahs0 - ah0;
        float e3 = __builtin_amdgcn_sqrtf(fmaf(vx, vx, ah1 * ah1));

        err += e1 + 0.1f * e2 + e3;
    }

    out[i] = err;
}

extern "C" void kernel_launch(void* const* d_in, const int* in_sizes, int n_in,
                              void* d_out, int out_size, void* d_ws, size_t ws_size,
                              hipStream_t stream) {
    const float* s_star = (const float*)d_in[0];
    const float* s0     = (const float*)d_in[1];
    const float* fc1_w  = (const float*)d_in[2];
    const float* fc1_b  = (const float*)d_in[3];
    const float* fc2_w  = (const float*)d_in[4];
    const float* fc2_b  = (const float*)d_in[5];
    const float* rc1_w  = (const float*)d_in[6];
    const float* rc1_b  = (const float*)d_in[7];
    const float* rc2_w  = (const float*)d_in[8];
    const float* rc2_b  = (const float*)d_in[9];
    const float* rc3_w  = (const float*)d_in[10];
    const float* rc3_b  = (const float*)d_in[11];
    const float* rr1_w  = (const float*)d_in[12];
    const float* rr1_b  = (const float*)d_in[13];
    const float* rr2_w  = (const float*)d_in[14];
    const float* rr2_b  = (const float*)d_in[15];
    const float* rr3_w  = (const float*)d_in[16];
    const float* rr3_b  = (const float*)d_in[17];
    float* out = (float*)d_out;

    int B = in_sizes[0] / 2;  // s_star is [B,2]
    int block = 256;
    int grid = (B + block - 1) / block;
    rollout_kernel<<<grid, block, 0, stream>>>(
        s_star, s0, fc1_w, fc1_b, fc2_w, fc2_b,
        rc1_w, rc1_b, rc2_w, rc2_b, rc3_w, rc3_b,
        rr1_w, rr1_b, rr2_w, rr2_b, rr3_w, rr3_b,
        out, B);
}

// Round 2
// 650.631 us; speedup vs baseline: 1.2042x; 1.2042x over previous
//
#include <hip/hip_runtime.h>

#define DT 0.1f
#define NSTEPS 10

typedef float v2f __attribute__((ext_vector_type(2)));

#if __has_builtin(__builtin_amdgcn_exp2f)
#define EXP2(x) __builtin_amdgcn_exp2f(x)
#else
#define EXP2(x) exp2f(x)
#endif

#if __has_builtin(__builtin_amdgcn_rcpf)
#define RCP(x) __builtin_amdgcn_rcpf(x)
#else
#define RCP(x) (1.0f / (x))
#endif

#if __has_builtin(__builtin_amdgcn_sqrtf)
#define SQRTF(x) __builtin_amdgcn_sqrtf(x)
#else
#define SQRTF(x) sqrtf(x)
#endif

static __device__ __forceinline__ v2f splat(float s) { v2f r; r.x = s; r.y = s; return r; }

static __device__ __forceinline__ v2f vfma(v2f a, v2f b, v2f c) {
    return __builtin_elementwise_fma(a, b, c);
}

// tanh of two independent values packed in a v2f.
// tanh(x) = 2/(1+e^{-2x}) - 1 ; e^{-2x} = exp2(-2*log2e*x)
// Shared-reciprocal: r = rcp(d0*d1); 1/d0 = r*d1 ; 1/d1 = r*d0.
// Clamp to +-10 so exp2 args stay in [-28.9, 28.9]: no inf -> no 0*inf NaN.
static __device__ __forceinline__ v2f tanh_pair(v2f x) {
    v2f xc = __builtin_elementwise_min(__builtin_elementwise_max(x, splat(-10.0f)), splat(10.0f));
    v2f t = xc * splat(-2.8853900818f);   // -2*log2(e)
    float e0 = EXP2(t.x);
    float e1 = EXP2(t.y);
    float d0 = e0 + 1.0f;
    float d1 = e1 + 1.0f;
    float r = RCP(d0 * d1);
    v2f inv; inv.x = r * d1; inv.y = r * d0;
    return vfma(inv, splat(2.0f), splat(-2.0f) * splat(0.5f));  // 2*inv - 1
}

// tanh-MLP 4->8->8->2 on a pair of rows (packed in v2f lanes).
static __device__ __forceinline__ void policy_pair(
    const float* __restrict__ w1, const float* __restrict__ b1,
    const float* __restrict__ w2, const float* __restrict__ b2,
    const float* __restrict__ w3, const float* __restrict__ b3,
    v2f c0, v2f c1, v2f c2, v2f c3,
    v2f& o0, v2f& o1)
{
    v2f h[8];
#pragma unroll
    for (int j = 0; j < 8; ++j) {
        v2f a = vfma(splat(w1[j * 4 + 0]), c0, splat(b1[j]));
        a = vfma(splat(w1[j * 4 + 1]), c1, a);
        a = vfma(splat(w1[j * 4 + 2]), c2, a);
        a = vfma(splat(w1[j * 4 + 3]), c3, a);
        h[j] = tanh_pair(a);
    }
    v2f g[8];
#pragma unroll
    for (int j = 0; j < 8; ++j) {
        v2f a = vfma(splat(w2[j * 8 + 0]), h[0], splat(b2[j]));
#pragma unroll
        for (int k = 1; k < 8; ++k) a = vfma(splat(w2[j * 8 + k]), h[k], a);
        g[j] = tanh_pair(a);
    }
    v2f t0 = vfma(splat(w3[0]), g[0], splat(b3[0]));
    v2f t1 = vfma(splat(w3[8]), g[0], splat(b3[1]));
#pragma unroll
    for (int k = 1; k < 8; ++k) {
        t0 = vfma(splat(w3[k]), g[k], t0);
        t1 = vfma(splat(w3[8 + k]), g[k], t1);
    }
    o0 = t0;
    o1 = t1;
}

__global__ void __launch_bounds__(256) rollout_kernel(
    const float* __restrict__ s_star, const float* __restrict__ s0,
    const float* __restrict__ fc1_w, const float* __restrict__ fc1_b,
    const float* __restrict__ fc2_w, const float* __restrict__ fc2_b,
    const float* __restrict__ rc1_w, const float* __restrict__ rc1_b,
    const float* __restrict__ rc2_w, const float* __restrict__ rc2_b,
    const float* __restrict__ rc3_w, const float* __restrict__ rc3_b,
    const float* __restrict__ rr1_w, const float* __restrict__ rr1_b,
    const float* __restrict__ rr2_w, const float* __restrict__ rr2_b,
    const float* __restrict__ rr3_w, const float* __restrict__ rr3_b,
    float* __restrict__ out, int NP)  // NP = number of row-pairs
{
    int i = blockIdx.x * blockDim.x + threadIdx.x;
    if (i >= NP) return;

    // rows 2i and 2i+1: one dwordx4 load each from s_star and s0
    float4 ssv = reinterpret_cast<const float4*>(s_star)[i];
    float4 s0v = reinterpret_cast<const float4*>(s0)[i];
    v2f ssx; ssx.x = ssv.x; ssx.y = ssv.z;
    v2f ssy; ssy.x = ssv.y; ssy.y = ssv.w;
    v2f sx;  sx.x  = s0v.x; sx.y  = s0v.z;
    v2f sy;  sy.x  = s0v.y; sy.y  = s0v.w;

    // Fuse linear predictor ah = fc2(fc1(x)) = A @ [s, s_star] + cb  (uniform A, cb)
    float A[2][4];
    float cb[2];
#pragma unroll
    for (int r = 0; r < 2; ++r) {
#pragma unroll
        for (int c = 0; c < 4; ++c) {
            float a = 0.0f;
#pragma unroll
            for (int j = 0; j < 4; ++j)
                a = fmaf(fc2_w[r * 4 + j], fc1_w[j * 4 + c], a);
            A[r][c] = a;
        }
        float b = fc2_b[r];
#pragma unroll
        for (int j = 0; j < 4; ++j) b = fmaf(fc2_w[r * 4 + j], fc1_b[j], b);
        cb[r] = b;
    }
    // s_star contribution is constant over steps (per-row)
    v2f d0 = vfma(splat(A[0][2]), ssx, vfma(splat(A[0][3]), ssy, splat(cb[0])));
    v2f d1 = vfma(splat(A[1][2]), ssx, vfma(splat(A[1][3]), ssy, splat(cb[1])));

    // ideal human action x-component: -1 if s_star.x > 0.5 else 1
    v2f ahs0;
    ahs0.x = (ssv.x > 0.5f) ? -1.0f : 1.0f;
    ahs0.y = (ssv.z > 0.5f) ? -1.0f : 1.0f;

    v2f err = splat(0.0f);

#pragma unroll 1
    for (int t = 0; t < NSTEPS; ++t) {
        v2f ah0 = vfma(splat(A[0][0]), sx, vfma(splat(A[0][1]), sy, d0));
        v2f ah1 = vfma(splat(A[1][0]), sx, vfma(splat(A[1][1]), sy, d1));

        v2f arr0, arr1, ar0, ar1;
        policy_pair(rr1_w, rr1_b, rr2_w, rr2_b, rr3_w, rr3_b,
                    sx, sy, ah0, ah1, arr0, arr1);
        policy_pair(rc1_w, rc1_b, rc2_w, rc2_b, rc3_w, rc3_b,
                    sx, sy, ah0, ah1, ar0, ar1);

        sx = vfma(splat(DT), ar0, sx);
        sy = vfma(splat(DT), ar1, sy);

        v2f dx = ssx - sx, dy = ssy - sy;
        v2f n1 = vfma(dx, dx, dy * dy);
        v2f ux = arr0 - ar0, uy = arr1 - ar1;
        v2f n2 = vfma(ux, ux, uy * uy);
        v2f vx = ahs0 - ah0;
        v2f n3 = vfma(vx, vx, ah1 * ah1);

        v2f e1; e1.x = SQRTF(n1.x); e1.y = SQRTF(n1.y);
        v2f e2; e2.x = SQRTF(n2.x); e2.y = SQRTF(n2.y);
        v2f e3; e3.x = SQRTF(n3.x); e3.y = SQRTF(n3.y);

        err = err + e1;
        err = vfma(splat(0.1f), e2, err);
        err = err + e3;
    }

    reinterpret_cast<float2*>(out)[i] = make_float2(err.x, err.y);
}

extern "C" void kernel_launch(void* const* d_in, const int* in_sizes, int n_in,
                              void* d_out, int out_size, void* d_ws, size_t ws_size,
                              hipStream_t stream) {
    const float* s_star = (const float*)d_in[0];
    const float* s0     = (const float*)d_in[1];
    const float* fc1_w  = (const float*)d_in[2];
    const float* fc1_b  = (const float*)d_in[3];
    const float* fc2_w  = (const float*)d_in[4];
    const float* fc2_b  = (const float*)d_in[5];
    const float* rc1_w  = (const float*)d_in[6];
    const float* rc1_b  = (const float*)d_in[7];
    const float* rc2_w  = (const float*)d_in[8];
    const float* rc2_b  = (const float*)d_in[9];
    const float* rc3_w  = (const float*)d_in[10];
    const float* rc3_b  = (const float*)d_in[11];
    const float* rr1_w  = (const float*)d_in[12];
    const float* rr1_b  = (const float*)d_in[13];
    const float* rr2_w  = (const float*)d_in[14];
    const float* rr2_b  = (const float*)d_in[15];
    const float* rr3_w  = (const float*)d_in[16];
    const float* rr3_b  = (const float*)d_in[17];
    float* out = (float*)d_out;

    int B = in_sizes[0] / 2;   // rows
    int NP = B / 2;            // row-pairs (B is even: 4194304)
    int block = 256;
    int grid = (NP + block - 1) / block;
    rollout_kernel<<<grid, block, 0, stream>>>(
        s_star, s0, fc1_w, fc1_b, fc2_w, fc2_b,
        rc1_w, rc1_b, rc2_w, rc2_b, rc3_w, rc3_b,
        rr1_w, rr1_b, rr2_w, rr2_b, rr3_w, rr3_b,
        out, NP);
}